// Round 9
// baseline (289.986 us; speedup 1.0000x reference)
//
#include <hip/hip_runtime.h>
#include <hip/hip_bf16.h>

typedef __bf16 bf16x8 __attribute__((ext_vector_type(8)));
typedef float  f32x4  __attribute__((ext_vector_type(4)));
typedef float  f32x16 __attribute__((ext_vector_type(16)));
typedef unsigned int u32x2 __attribute__((ext_vector_type(2)));

#define B_   2
#define T_   2048
#define D_   2048
#define QH_  16
#define KVH_ 4
#define HD_  128
#define BT_  (B_ * T_)
#define KVD_ 512
#define SCL  0.12751744f   // log2(e)/sqrt(128); folded into wq during cvt
#define NIF  -0.20762050593f  // -log2(10000)/64

// async global->LDS, 16B/lane; LDS dest = wave-uniform base + lane*16
#define GLOAD_LDS16(g, l)                                        \
  __builtin_amdgcn_global_load_lds(                              \
      (const __attribute__((address_space(1))) void*)(g),        \
      (__attribute__((address_space(3))) void*)(l), 16, 0, 0)

// chunk swizzles with row>>3 fold (rows differing by 8/16/24 -> distinct XOR)
#define SWZ(row)  ((((row) >> 3) ^ (row)) & 15)
#define SWZ8(row) ((((row) >> 3) ^ (row)) & 7)
// BK=32 rows are 64B (4 chunks); bank = (row&1)*16 + slot*4, so the swizzle
// must separate mrow>>1 classes, not mrow&3: slot = chunk ^ ((row>>1)&3).
#define SWZ4(row) (((row) >> 1) & 3)

// ---------------------------------------------------------------------------
// Fused fp32->bf16 conversion for all five inputs -> [xb|wqb|wkb|wvb|wob].
// ---------------------------------------------------------------------------
__global__ __launch_bounds__(256) void cvt_all(
    const float* __restrict__ x, const float* __restrict__ wq,
    const float* __restrict__ wk, const float* __restrict__ wv,
    const float* __restrict__ wo, ushort* __restrict__ out) {
  const int i = blockIdx.x * 256 + threadIdx.x;  // float4 idx; 4718592 total
  int j = i;
  const float* src;
  float mul = 1.f;
  if (j < 2097152) { src = x; }
  else if ((j -= 2097152) < 1048576) { src = wq; mul = SCL; }
  else if ((j -= 1048576) < 262144)  { src = wk; }
  else if ((j -= 262144) < 262144)   { src = wv; }
  else { j -= 262144; src = wo; }
  float4 v = ((const float4*)src)[j];
  __hip_bfloat16 h0 = __float2bfloat16(v.x * mul);
  __hip_bfloat16 h1 = __float2bfloat16(v.y * mul);
  __hip_bfloat16 h2 = __float2bfloat16(v.z * mul);
  __hip_bfloat16 h3 = __float2bfloat16(v.w * mul);
  ushort4 o;
  o.x = *(ushort*)&h0; o.y = *(ushort*)&h1;
  o.z = *(ushort*)&h2; o.w = *(ushort*)&h3;
  ((ushort4*)out)[i] = o;
}

// ---------------------------------------------------------------------------
// Fused QKV projection + RoPE. v3: BK=32 dbuf (32 KB) so all 768 blocks are
// co-resident at 3/CU (64 KB dbuf was 2/CU -> 512 resident + 256-block tail
// = ~33% idle). Counted vmcnt(4) keeps next tile's 4 loads in flight.
// RoPE epilogue in two row-half passes through a padded fp32 [64][130]
// buffer (33.3 KB total LDS; pad kills the 4-way write-bank aliasing).
// ---------------------------------------------------------------------------
__global__ __launch_bounds__(256, 2) void gemm_qkv(
    const ushort* __restrict__ X, const ushort* __restrict__ WQ,
    const ushort* __restrict__ WK, const ushort* __restrict__ WV,
    const int* __restrict__ positions,
    ushort* __restrict__ qo, ushort* __restrict__ ko, ushort* __restrict__ vo) {
  const int nb = blockIdx.x % 24;
  const int mb = blockIdx.x / 24;
  const int tid = threadIdx.x;
  const int wave = tid >> 6;
  const int lane = tid & 63;
  const int mrow = lane & 15;
  const int quad = lane >> 4;
  const int wm = wave >> 1;
  const int wn = wave & 1;
  const int m0 = mb * 128;
  const int K = D_;

  const ushort* Wg;
  if (nb < 16)      Wg = WQ + (size_t)nb * 128 * K;
  else if (nb < 20) Wg = WK + (size_t)(nb - 16) * 128 * K;
  else              Wg = WV + (size_t)(nb - 20) * 128 * K;

  // 33280 B: staging At[2][4096]|Bt[2][4096] (32 KB); epilogue fp32[64][130]
  __shared__ __align__(16) ushort smem[16640];
  ushort* Atp = smem;            // elem offsets: buf*4096
  ushort* Btp = smem + 8192;

  f32x4 acc[4][4];
#pragma unroll
  for (int i = 0; i < 4; ++i)
#pragma unroll
    for (int j = 0; j < 4; ++j) acc[i][j] = (f32x4){0.f, 0.f, 0.f, 0.f};

  const ushort* Xg = X + (size_t)m0 * K;

  auto STAGE = [&](int buf, int k0) {
#pragma unroll
    for (int p = 0; p < 2; ++p) {
      const int c = p * 256 + tid;
      const int row = c >> 2;                 // 4 chunks of 8 elems per row
      const int cc = (c & 3) ^ SWZ4(row);
      GLOAD_LDS16(Xg + (size_t)row * K + k0 + cc * 8,
                  Atp + (size_t)buf * 4096 + (size_t)(p * 256 + wave * 64) * 8);
      GLOAD_LDS16(Wg + (size_t)row * K + k0 + cc * 8,
                  Btp + (size_t)buf * 4096 + (size_t)(p * 256 + wave * 64) * 8);
    }
  };

  const int NT = K / 32;  // 64
  STAGE(0, 0);
  STAGE(1, 32);

  for (int t = 0; t < NT; ++t) {
    const int cur = t & 1;
    if (t + 2 < NT) asm volatile("s_waitcnt vmcnt(4)" ::: "memory");
    else            asm volatile("s_waitcnt vmcnt(0)" ::: "memory");
    __builtin_amdgcn_s_barrier();

    const ushort* Ac = Atp + (size_t)cur * 4096;
    const ushort* Bc = Btp + (size_t)cur * 4096;
    bf16x8 af[4], bfr[4];
#pragma unroll
    for (int mt = 0; mt < 4; ++mt) {
      const int row = wm * 64 + mt * 16 + mrow;
      af[mt] = *reinterpret_cast<const bf16x8*>(
          Ac + row * 32 + ((quad ^ SWZ4(row)) * 8));
    }
#pragma unroll
    for (int nt = 0; nt < 4; ++nt) {
      const int row = wn * 64 + nt * 16 + mrow;
      bfr[nt] = *reinterpret_cast<const bf16x8*>(
          Bc + row * 32 + ((quad ^ SWZ4(row)) * 8));
    }
#pragma unroll
    for (int mt = 0; mt < 4; ++mt)
#pragma unroll
      for (int nt = 0; nt < 4; ++nt)
        acc[mt][nt] = __builtin_amdgcn_mfma_f32_16x16x32_bf16(
            af[mt], bfr[nt], acc[mt][nt], 0, 0, 0);

    asm volatile("s_waitcnt lgkmcnt(0)" ::: "memory");
    __builtin_amdgcn_s_barrier();  // all waves done reading buf[cur]
    if (t + 2 < NT) STAGE(cur, (t + 2) * 32);
  }

  if (nb < 20) {
    // ---- fused RoPE epilogue, two row-half passes through 32.5 KB fp32 ----
    float* sC = (float*)smem;  // [64 rows][130 cols] (pad 2)
    ushort* outp; int ldo, colbase;
    if (nb < 16) { outp = qo; ldo = 2048; colbase = nb * 128; }
    else         { outp = ko; ldo = KVD_; colbase = (nb - 16) * 128; }

    const int col = tid & 63;                   // invariant
    const int wv = tid >> 6;
    const float inv = exp2f((float)col * NIF);  // 1/10000^(col/64)

#pragma unroll
    for (int rh = 0; rh < 2; ++rh) {
      if (wm == rh) {
#pragma unroll
        for (int mt = 0; mt < 4; ++mt)
#pragma unroll
          for (int nt = 0; nt < 4; ++nt) {
            const int colw = wn * 64 + nt * 16 + mrow;
            const int r0 = mt * 16 + quad * 4;
#pragma unroll
            for (int r = 0; r < 4; ++r)
              sC[(r0 + r) * 130 + colw] = acc[mt][nt][r];
          }
      }
      __syncthreads();
#pragma unroll 4
      for (int i = 0; i < 16; ++i) {
        const int rl = i * 4 + wv;
        const int grow = m0 + rh * 64 + rl;
        const float x1 = sC[rl * 130 + col];
        const float x2 = sC[rl * 130 + col + 64];
        const float pos = (float)positions[grow];
        const float ang = pos * inv;
        const float cc = cosf(ang);
        const float ss = sinf(ang);
        __hip_bfloat16 h1 = __float2bfloat16(x1 * cc - x2 * ss);
        __hip_bfloat16 h2 = __float2bfloat16(x1 * ss + x2 * cc);
        outp[(size_t)grow * ldo + colbase + col] = *(ushort*)&h1;
        outp[(size_t)grow * ldo + colbase + col + 64] = *(ushort*)&h2;
      }
      __syncthreads();
    }
  } else {
    // ---- V path: direct pre-transposed store (no rope) ----
#pragma unroll
    for (int mt = 0; mt < 4; ++mt) {
#pragma unroll
      for (int nt = 0; nt < 4; ++nt) {
        const int colw = wn * 64 + nt * 16 + mrow;
        const int row0 = m0 + wm * 64 + mt * 16 + quad * 4;
        const int col = (nb - 20) * 128 + colw;
        const int bb = row0 >> 11;
        const int t0 = row0 & (T_ - 1);
        ushort4 s4;
#pragma unroll
        for (int r = 0; r < 4; ++r) {
          __hip_bfloat16 hh = __float2bfloat16(acc[mt][nt][r]);
          (&s4.x)[r] = *(ushort*)&hh;
        }
        *(ushort4*)(vo + ((size_t)(bb * KVD_ + col)) * T_ + t0) = s4;
      }
    }
  }
}

// ---------------------------------------------------------------------------
// O-projection GEMM (fp32 out), 2-deep counted-vmcnt pipeline (BK=64).
// Grid 512 = all resident at 2/CU; no tail, left unchanged.
// ---------------------------------------------------------------------------
__global__ __launch_bounds__(256) void gemm_o(
    const ushort* __restrict__ X, const ushort* __restrict__ W,
    float* __restrict__ Y, int M, int N, int K) {
  const int nb128 = N >> 7;
  const int mb = blockIdx.x / nb128;
  const int nb = blockIdx.x % nb128;
  const int tid = threadIdx.x;
  const int wave = tid >> 6;
  const int lane = tid & 63;
  const int mrow = lane & 15;
  const int quad = lane >> 4;
  const int wm = wave >> 1;
  const int wn = wave & 1;
  const int m0 = mb * 128;
  const int n0 = nb * 128;

  __shared__ __align__(16) ushort At[2][128 * 64];
  __shared__ __align__(16) ushort Bt[2][128 * 64];

  f32x4 acc[4][4];
#pragma unroll
  for (int i = 0; i < 4; ++i)
#pragma unroll
    for (int j = 0; j < 4; ++j) acc[i][j] = (f32x4){0.f, 0.f, 0.f, 0.f};

  const ushort* Xg = X + (size_t)m0 * K;
  const ushort* Wg = W + (size_t)n0 * K;

  auto STAGE = [&](int buf, int k0) {
#pragma unroll
    for (int p = 0; p < 4; ++p) {
      const int c = p * 256 + tid;
      const int row = c >> 3;
      const int cc = (c & 7) ^ (row & 7);
      GLOAD_LDS16(Xg + (size_t)row * K + k0 + cc * 8,
                  At[buf] + (size_t)(p * 256 + wave * 64) * 8);
      GLOAD_LDS16(Wg + (size_t)row * K + k0 + cc * 8,
                  Bt[buf] + (size_t)(p * 256 + wave * 64) * 8);
    }
  };

  const int NT = K / 64;
  STAGE(0, 0);
  STAGE(1, 64);

  for (int t = 0; t < NT; ++t) {
    const int cur = t & 1;
    if (t + 2 < NT) asm volatile("s_waitcnt vmcnt(8)" ::: "memory");
    else            asm volatile("s_waitcnt vmcnt(0)" ::: "memory");
    __builtin_amdgcn_s_barrier();

    const ushort* Ac = At[cur];
    const ushort* Bc = Bt[cur];
#pragma unroll
    for (int s = 0; s < 2; ++s) {
      bf16x8 af[4], bfr[4];
#pragma unroll
      for (int mt = 0; mt < 4; ++mt) {
        const int row = wm * 64 + mt * 16 + mrow;
        af[mt] = *reinterpret_cast<const bf16x8*>(
            Ac + row * 64 + (((s * 4 + quad) ^ (row & 7)) * 8));
      }
#pragma unroll
      for (int nt = 0; nt < 4; ++nt) {
        const int row = wn * 64 + nt * 16 + mrow;
        bfr[nt] = *reinterpret_cast<const bf16x8*>(
            Bc + row * 64 + (((s * 4 + quad) ^ (row & 7)) * 8));
      }
#pragma unroll
      for (int mt = 0; mt < 4; ++mt)
#pragma unroll
        for (int nt = 0; nt < 4; ++nt)
          acc[mt][nt] = __builtin_amdgcn_mfma_f32_16x16x32_bf16(
              af[mt], bfr[nt], acc[mt][nt], 0, 0, 0);
    }

    asm volatile("s_waitcnt lgkmcnt(0)" ::: "memory");
    __builtin_amdgcn_s_barrier();
    if (t + 2 < NT) STAGE(cur, (t + 2) * 64);
  }

#pragma unroll
  for (int mt = 0; mt < 4; ++mt)
#pragma unroll
    for (int nt = 0; nt < 4; ++nt) {
      const int col = n0 + wn * 64 + nt * 16 + mrow;
      const int row0 = m0 + wm * 64 + mt * 16 + quad * 4;
#pragma unroll
      for (int r = 0; r < 4; ++r)
        Y[(size_t)(row0 + r) * N + col] = acc[mt][nt][r];
    }
}

// ---------------------------------------------------------------------------
// pack 2 f32 -> 1 u32 of 2 bf16 (compiler fuses to v_cvt_pk_bf16_f32)
// ---------------------------------------------------------------------------
static __device__ __forceinline__ unsigned pk2(float a, float b) {
  __hip_bfloat16 ha = __float2bfloat16(a);
  __hip_bfloat16 hb = __float2bfloat16(b);
  return (unsigned)(*(ushort*)&ha) | ((unsigned)(*(ushort*)&hb) << 16);
}

// exchange upper-32-lanes of a with lower-32-lanes of b
static __device__ __forceinline__ void hswap(unsigned& a, unsigned& b,
                                             const int hi) {
#if __has_builtin(__builtin_amdgcn_permlane32_swap)
  u32x2 r = __builtin_amdgcn_permlane32_swap(a, b, false, false);
  a = r.x;
  b = r.y;
#else
  unsigned s = __shfl_xor(hi ? a : b, 32, 64);
  unsigned na = hi ? s : a;
  b = hi ? b : s;
  a = na;
#endif
}

// ---------------------------------------------------------------------------
// Flash MFMA attention v10: balanced job pairing + dbuf counted-vmcnt
// pipeline. Grid 512: block pj handles qt = 63-pj then qt = pj -> exactly 33
// stage-iters per block. Block = 4 waves = 2 q-heads x 2 key-parities;
// parity partials combine by addition (exp2 softmax) in LDS epilogue.
// (256,2): VGPR ~96-115, no spill (the only sane launch-bounds config on
// this toolchain; any arg-2 of 4 pins VGPR=64 and spills).
// ---------------------------------------------------------------------------
__global__ __launch_bounds__(256, 2) void attn_mfma(
    const ushort* __restrict__ q, const ushort* __restrict__ k,
    const ushort* __restrict__ vt, ushort* __restrict__ ctx) {
  const int tid = threadIdx.x;
  const int wave = tid >> 6;
  const int lane = tid & 63;
  const int m5 = lane & 31;
  const int hi = lane >> 5;
  const int parity = wave & 1;   // which 32-key half of each 64-key stage
  const int hh = wave >> 1;      // q-head within head-pair, 0..1

  const int pj = blockIdx.x & 31;
  const int g  = blockIdx.x >> 5;  // 0..15
  const int b   = g >> 3;
  const int hkv = (g >> 1) & 3;
  const int hp  = g & 1;           // head-pair within kv group
  const int hq  = hkv * 4 + hp * 2 + hh;

  // 64 KB LDS: [K0 16K | V0 16K | K1 16K | V1 16K]; epilogue reuses first 32K
  __shared__ __align__(16) ushort smem[32768];
  __shared__ float lbuf[2][32];

  const ushort* kbase = k + ((size_t)b * T_ * KVH_ + hkv) * HD_;
  const ushort* vbase = vt + (size_t)(b * KVD_ + hkv * HD_) * T_;

  for (int job = 0; job < 2; ++job) {
    const int qt = job ? pj : 63 - pj;   // long first, then complementary
    const int q0 = qt * 32;
    const int ns = (qt >> 1) + 1;        // 64-key stage iterations

    // Q frags (B-operand): n=lane&31 (query), k = chunk*16 + hi*8 + j
    const ushort* qrow =
        q + ((size_t)(b * T_ + q0 + m5) * QH_ + hq) * HD_ + hi * 8;
    bf16x8 qf[8];
#pragma unroll
    for (int c = 0; c < 8; ++c)
      qf[c] = *reinterpret_cast<const bf16x8*>(qrow + c * 16);

    f32x16 o4[4];
#pragma unroll
    for (int dt = 0; dt < 4; ++dt)
#pragma unroll
      for (int r = 0; r < 16; ++r) o4[dt][r] = 0.f;
    float ls = 0.f;

    auto STAGE = [&](int buf, int s) {
      const int j0 = s * 64;
      ushort* kb_ = smem + buf * 16384;
      ushort* vb_ = smem + buf * 16384 + 8192;
#pragma unroll
      for (int p = 0; p < 4; ++p) {
        const int c = p * 256 + tid;
        const int krow = c >> 4;
        const int kco = (c & 15) ^ SWZ(krow);
        GLOAD_LDS16(kbase + (size_t)(j0 + krow) * KVD_ + kco * 8,
                    kb_ + (size_t)(p * 256 + wave * 64) * 8);
      }
#pragma unroll
      for (int p = 0; p < 4; ++p) {
        const int c = p * 256 + tid;
        const int vrow = c >> 3;
        const int vco = (c & 7) ^ SWZ8(vrow);
        GLOAD_LDS16(vbase + (size_t)vrow * T_ + j0 + vco * 8,
                    vb_ + (size_t)(p * 256 + wave * 64) * 8);
      }
    };

    STAGE(0, 0);

    for (int s = 0; s < ns; ++s) {
      const int cur = s & 1;
      if (s + 1 < ns) {
        STAGE(cur ^ 1, s + 1);  // 8 loads/thread stay in flight
        asm volatile("s_waitcnt vmcnt(8)" ::: "memory");
      } else {
        asm volatile("s_waitcnt vmcnt(0)" ::: "memory");
      }
      __builtin_amdgcn_s_barrier();

      const ushort* kt  = smem + cur * 16384;
      const ushort* vtl = smem + cur * 16384 + 8192;
      const int c32 = 2 * s + parity;  // this wave's 32-key chunk index

      if (c32 <= qt) {
        __builtin_amdgcn_s_setprio(1);
        // ---- S^T = K Q^T : A=K (m=key), B=Q (n=query) ----
        f32x16 sa;
#pragma unroll
        for (int r = 0; r < 16; ++r) sa[r] = 0.f;
        const int rowk = parity * 32 + m5;
#pragma unroll
        for (int c = 0; c < 8; ++c) {
          const int ch = (2 * c + hi) ^ SWZ(rowk);
          bf16x8 kf =
              *reinterpret_cast<const bf16x8*>(kt + rowk * 128 + ch * 8);
          sa = __builtin_amdgcn_mfma_f32_32x32x16_bf16(kf, qf[c], sa, 0, 0, 0);
        }

        // lane holds P[key_local = (r&3)+8*(r>>2)+4*hi][query = m5]
        float p[16];
        if (c32 == qt) {  // diagonal chunk
#pragma unroll
          for (int r = 0; r < 16; ++r) {
            const int roff = (r & 3) + 8 * (r >> 2) + 4 * hi;
            p[r] = (roff > m5) ? 0.f : exp2f(sa[r]);
          }
        } else {
#pragma unroll
          for (int r = 0; r < 16; ++r) p[r] = exp2f(sa[r]);
        }
#pragma unroll
        for (int r = 0; r < 16; ++r) ls += p[r];

        unsigned u0 = pk2(p[0], p[1]);   unsigned u1 = pk2(p[2], p[3]);
        unsigned u2 = pk2(p[4], p[5]);   unsigned u3 = pk2(p[6], p[7]);
        unsigned u4 = pk2(p[8], p[9]);   unsigned u5 = pk2(p[10], p[11]);
        unsigned u6 = pk2(p[12], p[13]); unsigned u7 = pk2(p[14], p[15]);
        hswap(u0, u2, hi); hswap(u1, u3, hi);
        hswap(u4, u6, hi); hswap(u5, u7, hi);

        // ---- O += P V ----
#pragma unroll
        for (int half = 0; half < 2; ++half) {
          union { unsigned w[4]; bf16x8 v; } pa;
          pa.w[0] = half ? u4 : u0;
          pa.w[1] = half ? u5 : u1;
          pa.w[2] = half ? u6 : u2;
          pa.w[3] = half ? u7 : u3;
          const int gc2 = parity * 4 + half * 2;  // 8-key chunk base in vtl
#pragma unroll
          for (int dt = 0; dt < 4; ++dt) {
            const int rowv = dt * 32 + m5;
            const int chv = (gc2 + hi) ^ SWZ8(rowv);
            bf16x8 vf =
                *reinterpret_cast<const bf16x8*>(vtl + rowv * 64 + chv * 8);
            o4[dt] = __builtin_amdgcn_mfma_f32_32x32x16_bf16(pa.v, vf, o4[dt],
                                                             0, 0, 0);
          }
        }
        __builtin_amdgcn_s_setprio(0);
      }

      asm volatile("s_waitcnt lgkmcnt(0)" ::: "memory");
      __builtin_amdgcn_s_barrier();  // all waves done reading buf[cur]
    }

    // ---- epilogue: combine parity partials via LDS (reuses buf0 region) ----
    const float lt = ls + __shfl_xor(ls, 32, 64);
    float* sO = (float*)smem;  // [2 hh][32 q][128 d] fp32 = 32 KB
    if (parity) {
#pragma unroll
      for (int reg = 0; reg < 16; ++reg) {
        const int qrw = (reg & 3) + 8 * (reg >> 2) + 4 * hi;
#pragma unroll
        for (int dt = 0; dt < 4; ++dt)
          sO[hh * 4096 + qrw * 128 + dt * 32 + m5] = o4[dt][reg];
      }
      if (hi == 0) lbuf[hh][m5] = lt;
    }
    __syncthreads();
    if (!parity) {
      const float ltot = lt + lbuf[hh][m5];
#pragma unroll
      for (int reg = 0; reg < 16; ++reg) {
        const int qrw = (reg & 3) + 8 * (reg >> 2) + 4 * hi;
        const float rl = 1.f / __shfl(ltot, qrw, 64);
        ushort* op =
            ctx + ((size_t)(b * T_ + q0 + qrw) * QH_ + hq) * HD_ + m5;
#pragma unroll
        for (int dt = 0; dt < 4; ++dt) {
          const float ov =
              o4[dt][reg] + sO[hh * 4096 + qrw * 128 + dt * 32 + m5];
          __hip_bfloat16 hb = __float2bfloat16(ov * rl);
          op[dt * 32] = *(ushort*)&hb;
        }
      }
    }
    __syncthreads();  // epilogue reads done before next job restages buf0
  }
}

// ---------------------------------------------------------------------------
extern "C" void kernel_launch(void* const* d_in, const int* in_sizes, int n_in,
                              void* d_out, int out_size, void* d_ws, size_t ws_size,
                              hipStream_t stream) {
  const float* x  = (const float*)d_in[0];
  const int* pos  = (const int*)d_in[1];
  const float* wq = (const float*)d_in[2];
  const float* wk = (const float*)d_in[3];
  const float* wv = (const float*)d_in[4];
  const float* wo = (const float*)d_in[5];

  // Workspace (bf16 elements), 60 MB. Order must match cvt_all's segments.
  ushort* xb  = (ushort*)d_ws;              // 8388608 (reused as ctx)
  ushort* wqb = xb  + (size_t)8388608;      // 4194304
  ushort* wkb = wqb + (size_t)4194304;      // 1048576
  ushort* wvb = wkb + (size_t)1048576;      // 1048576
  ushort* wob = wvb + (size_t)1048576;      // 4194304
  ushort* qb  = wob + (size_t)4194304;      // 8388608
  ushort* kb  = qb  + (size_t)8388608;      // 2097152
  ushort* vtb = kb  + (size_t)2097152;      // 2097152
  ushort* ctx = xb;  // xb dead after gemm_qkv

  // fused fp32->bf16 conversions (wq pre-scaled by SCL)
  cvt_all<<<18432, 256, 0, stream>>>(x, wq, wk, wv, wo, (ushort*)d_ws);

  // fused QKV projection + RoPE (V written pre-transposed)
  gemm_qkv<<<(BT_ / 128) * 24, 256, 0, stream>>>(
      xb, wqb, wkb, wvb, pos, qb, kb, vtb);

  // flash MFMA attention -> ctx (512 wgs, complementary-qt pairs, dbuf K/V)
  attn_mfma<<<512, 256, 0, stream>>>(qb, kb, vtb, ctx);

  // output projection -> fp32 d_out
  gemm_o<<<(BT_ / 128) * (D_ / 128), 256, 0, stream>>>(
      ctx, wob, (float*)d_out, BT_, D_, QH_ * HD_);
}

// Round 10
// 278.700 us; speedup vs baseline: 1.0405x; 1.0405x over previous
//
#include <hip/hip_runtime.h>
#include <hip/hip_bf16.h>

typedef __bf16 bf16x8 __attribute__((ext_vector_type(8)));
typedef float  f32x4  __attribute__((ext_vector_type(4)));
typedef float  f32x16 __attribute__((ext_vector_type(16)));
typedef unsigned int u32x2 __attribute__((ext_vector_type(2)));

#define B_   2
#define T_   2048
#define D_   2048
#define QH_  16
#define KVH_ 4
#define HD_  128
#define BT_  (B_ * T_)
#define KVD_ 512
#define SCL  0.12751744f   // log2(e)/sqrt(128); folded into wq during cvt
#define NIF  -0.20762050593f  // -log2(10000)/64

// async global->LDS, 16B/lane; LDS dest = wave-uniform base + lane*16
#define GLOAD_LDS16(g, l)                                        \
  __builtin_amdgcn_global_load_lds(                              \
      (const __attribute__((address_space(1))) void*)(g),        \
      (__attribute__((address_space(3))) void*)(l), 16, 0, 0)

// chunk swizzles with row>>3 fold (rows differing by 8/16/24 -> distinct XOR)
#define SWZ(row)  ((((row) >> 3) ^ (row)) & 15)
#define SWZ8(row) ((((row) >> 3) ^ (row)) & 7)

// ---------------------------------------------------------------------------
// Fused fp32->bf16 conversion for all five inputs -> [xb|wqb|wkb|wvb|wob].
// ---------------------------------------------------------------------------
__global__ __launch_bounds__(256) void cvt_all(
    const float* __restrict__ x, const float* __restrict__ wq,
    const float* __restrict__ wk, const float* __restrict__ wv,
    const float* __restrict__ wo, ushort* __restrict__ out) {
  const int i = blockIdx.x * 256 + threadIdx.x;  // float4 idx; 4718592 total
  int j = i;
  const float* src;
  float mul = 1.f;
  if (j < 2097152) { src = x; }
  else if ((j -= 2097152) < 1048576) { src = wq; mul = SCL; }
  else if ((j -= 1048576) < 262144)  { src = wk; }
  else if ((j -= 262144) < 262144)   { src = wv; }
  else { j -= 262144; src = wo; }
  float4 v = ((const float4*)src)[j];
  __hip_bfloat16 h0 = __float2bfloat16(v.x * mul);
  __hip_bfloat16 h1 = __float2bfloat16(v.y * mul);
  __hip_bfloat16 h2 = __float2bfloat16(v.z * mul);
  __hip_bfloat16 h3 = __float2bfloat16(v.w * mul);
  ushort4 o;
  o.x = *(ushort*)&h0; o.y = *(ushort*)&h1;
  o.z = *(ushort*)&h2; o.w = *(ushort*)&h3;
  ((ushort4*)out)[i] = o;
}

// ---------------------------------------------------------------------------
// Fused QKV projection + RoPE, 128x128 tile, BK=64 (R8 structure — BK=32
// regressed: occupancy rose to 25% but halved MFMA-per-barrier lost more).
// 2-deep counted-vmcnt pipeline. NEW: XCD-aware block swizzle — each XCD
// gets 4 contiguous mb-tiles, so the 24 same-mb blocks (sharing a 0.5 MB
// X-panel) land on ONE XCD's L2 instead of all 8 (latency-bound kernel:
// HBM-miss ~900cyc -> L2-hit ~200cyc inside the vmcnt wait).
// ---------------------------------------------------------------------------
__global__ __launch_bounds__(256) void gemm_qkv(
    const ushort* __restrict__ X, const ushort* __restrict__ WQ,
    const ushort* __restrict__ WK, const ushort* __restrict__ WV,
    const int* __restrict__ positions,
    ushort* __restrict__ qo, ushort* __restrict__ ko, ushort* __restrict__ vo) {
  // bijective XCD swizzle: 768 blocks = 8 xcd x 96; mb = xcd*4 + r/24
  const int bid = blockIdx.x;
  const int r_  = bid >> 3;
  const int mb  = (bid & 7) * 4 + r_ / 24;
  const int nb  = r_ % 24;
  const int tid = threadIdx.x;
  const int wave = tid >> 6;
  const int lane = tid & 63;
  const int mrow = lane & 15;
  const int quad = lane >> 4;
  const int wm = wave >> 1;
  const int wn = wave & 1;
  const int m0 = mb * 128;
  const int K = D_;

  const ushort* Wg;
  if (nb < 16)      Wg = WQ + (size_t)nb * 128 * K;
  else if (nb < 20) Wg = WK + (size_t)(nb - 16) * 128 * K;
  else              Wg = WV + (size_t)(nb - 20) * 128 * K;

  // 64 KB: At dbuf (2x16KB) | Bt dbuf (2x16KB); reused as fp32 C-tile.
  __shared__ __align__(16) ushort smem[32768];
  ushort* Atp = smem;            // [2][128*64]
  ushort* Btp = smem + 16384;    // [2][128*64]

  f32x4 acc[4][4];
#pragma unroll
  for (int i = 0; i < 4; ++i)
#pragma unroll
    for (int j = 0; j < 4; ++j) acc[i][j] = (f32x4){0.f, 0.f, 0.f, 0.f};

  const ushort* Xg = X + (size_t)m0 * K;

  auto STAGE = [&](int buf, int k0) {
#pragma unroll
    for (int p = 0; p < 4; ++p) {
      const int c = p * 256 + tid;
      const int row = c >> 3;
      const int cc = (c & 7) ^ (row & 7);
      GLOAD_LDS16(Xg + (size_t)row * K + k0 + cc * 8,
                  Atp + (size_t)buf * 8192 + (size_t)(p * 256 + wave * 64) * 8);
      GLOAD_LDS16(Wg + (size_t)row * K + k0 + cc * 8,
                  Btp + (size_t)buf * 8192 + (size_t)(p * 256 + wave * 64) * 8);
    }
  };

  const int NT = K / 64;  // 32
  STAGE(0, 0);
  STAGE(1, 64);

  for (int t = 0; t < NT; ++t) {
    const int cur = t & 1;
    if (t + 2 < NT) asm volatile("s_waitcnt vmcnt(8)" ::: "memory");
    else            asm volatile("s_waitcnt vmcnt(0)" ::: "memory");
    __builtin_amdgcn_s_barrier();

    const ushort* Ac = Atp + (size_t)cur * 8192;
    const ushort* Bc = Btp + (size_t)cur * 8192;
#pragma unroll
    for (int s = 0; s < 2; ++s) {
      bf16x8 af[4], bfr[4];
#pragma unroll
      for (int mt = 0; mt < 4; ++mt) {
        const int row = wm * 64 + mt * 16 + mrow;
        af[mt] = *reinterpret_cast<const bf16x8*>(
            Ac + row * 64 + (((s * 4 + quad) ^ (row & 7)) * 8));
      }
#pragma unroll
      for (int nt = 0; nt < 4; ++nt) {
        const int row = wn * 64 + nt * 16 + mrow;
        bfr[nt] = *reinterpret_cast<const bf16x8*>(
            Bc + row * 64 + (((s * 4 + quad) ^ (row & 7)) * 8));
      }
#pragma unroll
      for (int mt = 0; mt < 4; ++mt)
#pragma unroll
        for (int nt = 0; nt < 4; ++nt)
          acc[mt][nt] = __builtin_amdgcn_mfma_f32_16x16x32_bf16(
              af[mt], bfr[nt], acc[mt][nt], 0, 0, 0);
    }

    asm volatile("s_waitcnt lgkmcnt(0)" ::: "memory");
    __builtin_amdgcn_s_barrier();  // all waves done reading buf[cur]
    if (t + 2 < NT) STAGE(cur, (t + 2) * 64);
  }

  if (nb < 20) {
    // ---- fused RoPE epilogue (Q and K heads) ----
    float* sC = (float*)smem;  // [128 rows][128 cols] fp32 = 64 KB
#pragma unroll
    for (int mt = 0; mt < 4; ++mt)
#pragma unroll
      for (int nt = 0; nt < 4; ++nt) {
        const int colw = wn * 64 + nt * 16 + mrow;
        const int rl0 = wm * 64 + mt * 16 + quad * 4;
#pragma unroll
        for (int r = 0; r < 4; ++r)
          sC[(rl0 + r) * 128 + colw] = acc[mt][nt][r];
      }
    __syncthreads();

    ushort* outp; int ldo, colbase;
    if (nb < 16) { outp = qo; ldo = 2048; colbase = nb * 128; }
    else         { outp = ko; ldo = KVD_; colbase = (nb - 16) * 128; }

    const int col = tid & 63;                       // invariant across i
    const float inv = exp2f((float)col * NIF);      // 1/10000^(col/64)
#pragma unroll 4
    for (int i = 0; i < 32; ++i) {
      const int row = i * 4 + (tid >> 6);
      const float x1 = sC[row * 128 + col];
      const float x2 = sC[row * 128 + col + 64];
      const float pos = (float)positions[m0 + row];
      const float ang = pos * inv;
      const float cc = cosf(ang);
      const float ss = sinf(ang);
      __hip_bfloat16 h1 = __float2bfloat16(x1 * cc - x2 * ss);
      __hip_bfloat16 h2 = __float2bfloat16(x1 * ss + x2 * cc);
      outp[(size_t)(m0 + row) * ldo + colbase + col] = *(ushort*)&h1;
      outp[(size_t)(m0 + row) * ldo + colbase + col + 64] = *(ushort*)&h2;
    }
  } else {
    // ---- V path: direct pre-transposed store (no rope) ----
#pragma unroll
    for (int mt = 0; mt < 4; ++mt) {
#pragma unroll
      for (int nt = 0; nt < 4; ++nt) {
        const int colw = wn * 64 + nt * 16 + mrow;
        const int row0 = m0 + wm * 64 + mt * 16 + quad * 4;
        const int col = (nb - 20) * 128 + colw;
        const int bb = row0 >> 11;
        const int t0 = row0 & (T_ - 1);
        ushort4 s4;
#pragma unroll
        for (int r = 0; r < 4; ++r) {
          __hip_bfloat16 hh = __float2bfloat16(acc[mt][nt][r]);
          (&s4.x)[r] = *(ushort*)&hh;
        }
        *(ushort4*)(vo + ((size_t)(bb * KVD_ + col)) * T_ + t0) = s4;
      }
    }
  }
}

// ---------------------------------------------------------------------------
// O-projection GEMM (fp32 out), 2-deep counted-vmcnt pipeline (BK=64).
// XCD swizzle: 512 blocks = 8 xcd x 64; each XCD gets 4 contiguous mb-tiles
// (same-mb blocks share the 0.5 MB ctx panel).
// ---------------------------------------------------------------------------
__global__ __launch_bounds__(256) void gemm_o(
    const ushort* __restrict__ X, const ushort* __restrict__ W,
    float* __restrict__ Y, int M, int N, int K) {
  // grid fixed at 32 mb x 16 nb = 512
  const int bid = blockIdx.x;
  const int r_  = bid >> 3;
  const int mb  = (bid & 7) * 4 + (r_ >> 4);
  const int nb  = r_ & 15;
  const int tid = threadIdx.x;
  const int wave = tid >> 6;
  const int lane = tid & 63;
  const int mrow = lane & 15;
  const int quad = lane >> 4;
  const int wm = wave >> 1;
  const int wn = wave & 1;
  const int m0 = mb * 128;
  const int n0 = nb * 128;

  __shared__ __align__(16) ushort At[2][128 * 64];
  __shared__ __align__(16) ushort Bt[2][128 * 64];

  f32x4 acc[4][4];
#pragma unroll
  for (int i = 0; i < 4; ++i)
#pragma unroll
    for (int j = 0; j < 4; ++j) acc[i][j] = (f32x4){0.f, 0.f, 0.f, 0.f};

  const ushort* Xg = X + (size_t)m0 * K;
  const ushort* Wg = W + (size_t)n0 * K;

  auto STAGE = [&](int buf, int k0) {
#pragma unroll
    for (int p = 0; p < 4; ++p) {
      const int c = p * 256 + tid;
      const int row = c >> 3;
      const int cc = (c & 7) ^ (row & 7);
      GLOAD_LDS16(Xg + (size_t)row * K + k0 + cc * 8,
                  At[buf] + (size_t)(p * 256 + wave * 64) * 8);
      GLOAD_LDS16(Wg + (size_t)row * K + k0 + cc * 8,
                  Bt[buf] + (size_t)(p * 256 + wave * 64) * 8);
    }
  };

  const int NT = K / 64;
  STAGE(0, 0);
  STAGE(1, 64);

  for (int t = 0; t < NT; ++t) {
    const int cur = t & 1;
    if (t + 2 < NT) asm volatile("s_waitcnt vmcnt(8)" ::: "memory");
    else            asm volatile("s_waitcnt vmcnt(0)" ::: "memory");
    __builtin_amdgcn_s_barrier();

    const ushort* Ac = At[cur];
    const ushort* Bc = Bt[cur];
#pragma unroll
    for (int s = 0; s < 2; ++s) {
      bf16x8 af[4], bfr[4];
#pragma unroll
      for (int mt = 0; mt < 4; ++mt) {
        const int row = wm * 64 + mt * 16 + mrow;
        af[mt] = *reinterpret_cast<const bf16x8*>(
            Ac + row * 64 + (((s * 4 + quad) ^ (row & 7)) * 8));
      }
#pragma unroll
      for (int nt = 0; nt < 4; ++nt) {
        const int row = wn * 64 + nt * 16 + mrow;
        bfr[nt] = *reinterpret_cast<const bf16x8*>(
            Bc + row * 64 + (((s * 4 + quad) ^ (row & 7)) * 8));
      }
#pragma unroll
      for (int mt = 0; mt < 4; ++mt)
#pragma unroll
        for (int nt = 0; nt < 4; ++nt)
          acc[mt][nt] = __builtin_amdgcn_mfma_f32_16x16x32_bf16(
              af[mt], bfr[nt], acc[mt][nt], 0, 0, 0);
    }

    asm volatile("s_waitcnt lgkmcnt(0)" ::: "memory");
    __builtin_amdgcn_s_barrier();
    if (t + 2 < NT) STAGE(cur, (t + 2) * 64);
  }

#pragma unroll
  for (int mt = 0; mt < 4; ++mt)
#pragma unroll
    for (int nt = 0; nt < 4; ++nt) {
      const int col = n0 + wn * 64 + nt * 16 + mrow;
      const int row0 = m0 + wm * 64 + mt * 16 + quad * 4;
#pragma unroll
      for (int r = 0; r < 4; ++r)
        Y[(size_t)(row0 + r) * N + col] = acc[mt][nt][r];
    }
}

// ---------------------------------------------------------------------------
// pack 2 f32 -> 1 u32 of 2 bf16 (compiler fuses to v_cvt_pk_bf16_f32)
// ---------------------------------------------------------------------------
static __device__ __forceinline__ unsigned pk2(float a, float b) {
  __hip_bfloat16 ha = __float2bfloat16(a);
  __hip_bfloat16 hb = __float2bfloat16(b);
  return (unsigned)(*(ushort*)&ha) | ((unsigned)(*(ushort*)&hb) << 16);
}

// exchange upper-32-lanes of a with lower-32-lanes of b
static __device__ __forceinline__ void hswap(unsigned& a, unsigned& b,
                                             const int hi) {
#if __has_builtin(__builtin_amdgcn_permlane32_swap)
  u32x2 r = __builtin_amdgcn_permlane32_swap(a, b, false, false);
  a = r.x;
  b = r.y;
#else
  unsigned s = __shfl_xor(hi ? a : b, 32, 64);
  unsigned na = hi ? s : a;
  b = hi ? b : s;
  a = na;
#endif
}

// ---------------------------------------------------------------------------
// Flash MFMA attention v10: balanced job pairing + dbuf counted-vmcnt
// pipeline. Grid 512: block pj handles qt = 63-pj then qt = pj -> exactly 33
// stage-iters per block. Block = 4 waves = 2 q-heads x 2 key-parities;
// parity partials combine by addition (exp2 softmax) in LDS epilogue.
// (256,2): VGPR ~96-115, no spill (the only sane launch-bounds config on
// this toolchain; any arg-2 of 4 pins VGPR=64 and spills).
// ---------------------------------------------------------------------------
__global__ __launch_bounds__(256, 2) void attn_mfma(
    const ushort* __restrict__ q, const ushort* __restrict__ k,
    const ushort* __restrict__ vt, ushort* __restrict__ ctx) {
  const int tid = threadIdx.x;
  const int wave = tid >> 6;
  const int lane = tid & 63;
  const int m5 = lane & 31;
  const int hi = lane >> 5;
  const int parity = wave & 1;   // which 32-key half of each 64-key stage
  const int hh = wave >> 1;      // q-head within head-pair, 0..1

  const int pj = blockIdx.x & 31;
  const int g  = blockIdx.x >> 5;  // 0..15
  const int b   = g >> 3;
  const int hkv = (g >> 1) & 3;
  const int hp  = g & 1;           // head-pair within kv group
  const int hq  = hkv * 4 + hp * 2 + hh;

  // 64 KB LDS: [K0 16K | V0 16K | K1 16K | V1 16K]; epilogue reuses first 32K
  __shared__ __align__(16) ushort smem[32768];
  __shared__ float lbuf[2][32];

  const ushort* kbase = k + ((size_t)b * T_ * KVH_ + hkv) * HD_;
  const ushort* vbase = vt + (size_t)(b * KVD_ + hkv * HD_) * T_;

  for (int job = 0; job < 2; ++job) {
    const int qt = job ? pj : 63 - pj;   // long first, then complementary
    const int q0 = qt * 32;
    const int ns = (qt >> 1) + 1;        // 64-key stage iterations

    // Q frags (B-operand): n=lane&31 (query), k = chunk*16 + hi*8 + j
    const ushort* qrow =
        q + ((size_t)(b * T_ + q0 + m5) * QH_ + hq) * HD_ + hi * 8;
    bf16x8 qf[8];
#pragma unroll
    for (int c = 0; c < 8; ++c)
      qf[c] = *reinterpret_cast<const bf16x8*>(qrow + c * 16);

    f32x16 o4[4];
#pragma unroll
    for (int dt = 0; dt < 4; ++dt)
#pragma unroll
      for (int r = 0; r < 16; ++r) o4[dt][r] = 0.f;
    float ls = 0.f;

    auto STAGE = [&](int buf, int s) {
      const int j0 = s * 64;
      ushort* kb_ = smem + buf * 16384;
      ushort* vb_ = smem + buf * 16384 + 8192;
#pragma unroll
      for (int p = 0; p < 4; ++p) {
        const int c = p * 256 + tid;
        const int krow = c >> 4;
        const int kco = (c & 15) ^ SWZ(krow);
        GLOAD_LDS16(kbase + (size_t)(j0 + krow) * KVD_ + kco * 8,
                    kb_ + (size_t)(p * 256 + wave * 64) * 8);
      }
#pragma unroll
      for (int p = 0; p < 4; ++p) {
        const int c = p * 256 + tid;
        const int vrow = c >> 3;
        const int vco = (c & 7) ^ SWZ8(vrow);
        GLOAD_LDS16(vbase + (size_t)vrow * T_ + j0 + vco * 8,
                    vb_ + (size_t)(p * 256 + wave * 64) * 8);
      }
    };

    STAGE(0, 0);

    for (int s = 0; s < ns; ++s) {
      const int cur = s & 1;
      if (s + 1 < ns) {
        STAGE(cur ^ 1, s + 1);  // 8 loads/thread stay in flight
        asm volatile("s_waitcnt vmcnt(8)" ::: "memory");
      } else {
        asm volatile("s_waitcnt vmcnt(0)" ::: "memory");
      }
      __builtin_amdgcn_s_barrier();

      const ushort* kt  = smem + cur * 16384;
      const ushort* vtl = smem + cur * 16384 + 8192;
      const int c32 = 2 * s + parity;  // this wave's 32-key chunk index

      if (c32 <= qt) {
        __builtin_amdgcn_s_setprio(1);
        // ---- S^T = K Q^T : A=K (m=key), B=Q (n=query) ----
        f32x16 sa;
#pragma unroll
        for (int r = 0; r < 16; ++r) sa[r] = 0.f;
        const int rowk = parity * 32 + m5;
#pragma unroll
        for (int c = 0; c < 8; ++c) {
          const int ch = (2 * c + hi) ^ SWZ(rowk);
          bf16x8 kf =
              *reinterpret_cast<const bf16x8*>(kt + rowk * 128 + ch * 8);
          sa = __builtin_amdgcn_mfma_f32_32x32x16_bf16(kf, qf[c], sa, 0, 0, 0);
        }

        // lane holds P[key_local = (r&3)+8*(r>>2)+4*hi][query = m5]
        float p[16];
        if (c32 == qt) {  // diagonal chunk
#pragma unroll
          for (int r = 0; r < 16; ++r) {
            const int roff = (r & 3) + 8 * (r >> 2) + 4 * hi;
            p[r] = (roff > m5) ? 0.f : exp2f(sa[r]);
          }
        } else {
#pragma unroll
          for (int r = 0; r < 16; ++r) p[r] = exp2f(sa[r]);
        }
#pragma unroll
        for (int r = 0; r < 16; ++r) ls += p[r];

        unsigned u0 = pk2(p[0], p[1]);   unsigned u1 = pk2(p[2], p[3]);
        unsigned u2 = pk2(p[4], p[5]);   unsigned u3 = pk2(p[6], p[7]);
        unsigned u4 = pk2(p[8], p[9]);   unsigned u5 = pk2(p[10], p[11]);
        unsigned u6 = pk2(p[12], p[13]); unsigned u7 = pk2(p[14], p[15]);
        hswap(u0, u2, hi); hswap(u1, u3, hi);
        hswap(u4, u6, hi); hswap(u5, u7, hi);

        // ---- O += P V ----
#pragma unroll
        for (int half = 0; half < 2; ++half) {
          union { unsigned w[4]; bf16x8 v; } pa;
          pa.w[0] = half ? u4 : u0;
          pa.w[1] = half ? u5 : u1;
          pa.w[2] = half ? u6 : u2;
          pa.w[3] = half ? u7 : u3;
          const int gc2 = parity * 4 + half * 2;  // 8-key chunk base in vtl
#pragma unroll
          for (int dt = 0; dt < 4; ++dt) {
            const int rowv = dt * 32 + m5;
            const int chv = (gc2 + hi) ^ SWZ8(rowv);
            bf16x8 vf =
                *reinterpret_cast<const bf16x8*>(vtl + rowv * 64 + chv * 8);
            o4[dt] = __builtin_amdgcn_mfma_f32_32x32x16_bf16(pa.v, vf, o4[dt],
                                                             0, 0, 0);
          }
        }
        __builtin_amdgcn_s_setprio(0);
      }

      asm volatile("s_waitcnt lgkmcnt(0)" ::: "memory");
      __builtin_amdgcn_s_barrier();  // all waves done reading buf[cur]
    }

    // ---- epilogue: combine parity partials via LDS (reuses buf0 region) ----
    const float lt = ls + __shfl_xor(ls, 32, 64);
    float* sO = (float*)smem;  // [2 hh][32 q][128 d] fp32 = 32 KB
    if (parity) {
#pragma unroll
      for (int reg = 0; reg < 16; ++reg) {
        const int qrw = (reg & 3) + 8 * (reg >> 2) + 4 * hi;
#pragma unroll
        for (int dt = 0; dt < 4; ++dt)
          sO[hh * 4096 + qrw * 128 + dt * 32 + m5] = o4[dt][reg];
      }
      if (hi == 0) lbuf[hh][m5] = lt;
    }
    __syncthreads();
    if (!parity) {
      const float ltot = lt + lbuf[hh][m5];
#pragma unroll
      for (int reg = 0; reg < 16; ++reg) {
        const int qrw = (reg & 3) + 8 * (reg >> 2) + 4 * hi;
        const float rl = 1.f / __shfl(ltot, qrw, 64);
        ushort* op =
            ctx + ((size_t)(b * T_ + q0 + qrw) * QH_ + hq) * HD_ + m5;
#pragma unroll
        for (int dt = 0; dt < 4; ++dt) {
          const float ov =
              o4[dt][reg] + sO[hh * 4096 + qrw * 128 + dt * 32 + m5];
          __hip_bfloat16 hb = __float2bfloat16(ov * rl);
          op[dt * 32] = *(ushort*)&hb;
        }
      }
    }
    __syncthreads();  // epilogue reads done before next job restages buf0
  }
}

// ---------------------------------------------------------------------------
extern "C" void kernel_launch(void* const* d_in, const int* in_sizes, int n_in,
                              void* d_out, int out_size, void* d_ws, size_t ws_size,
                              hipStream_t stream) {
  const float* x  = (const float*)d_in[0];
  const int* pos  = (const int*)d_in[1];
  const float* wq = (const float*)d_in[2];
  const float* wk = (const float*)d_in[3];
  const float* wv = (const float*)d_in[4];
  const float* wo = (const float*)d_in[5];

  // Workspace (bf16 elements), 60 MB. Order must match cvt_all's segments.
  ushort* xb  = (ushort*)d_ws;              // 8388608 (reused as ctx)
  ushort* wqb = xb  + (size_t)8388608;      // 4194304
  ushort* wkb = wqb + (size_t)4194304;      // 1048576
  ushort* wvb = wkb + (size_t)1048576;      // 1048576
  ushort* wob = wvb + (size_t)1048576;      // 4194304
  ushort* qb  = wob + (size_t)4194304;      // 8388608
  ushort* kb  = qb  + (size_t)8388608;      // 2097152
  ushort* vtb = kb  + (size_t)2097152;      // 2097152
  ushort* ctx = xb;  // xb dead after gemm_qkv

  // fused fp32->bf16 conversions (wq pre-scaled by SCL)
  cvt_all<<<18432, 256, 0, stream>>>(x, wq, wk, wv, wo, (ushort*)d_ws);

  // fused QKV projection + RoPE (V written pre-transposed), XCD-swizzled
  gemm_qkv<<<(BT_ / 128) * 24, 256, 0, stream>>>(
      xb, wqb, wkb, wvb, pos, qb, kb, vtb);

  // flash MFMA attention -> ctx (512 wgs, complementary-qt pairs, dbuf K/V)
  attn_mfma<<<512, 256, 0, stream>>>(qb, kb, vtb, ctx);

  // output projection -> fp32 d_out, XCD-swizzled
  gemm_o<<<(BT_ / 128) * (D_ / 128), 256, 0, stream>>>(
      ctx, wob, (float*)d_out, BT_, D_, QH_ * HD_);
}